// Round 7
// baseline (1232.258 us; speedup 1.0000x reference)
//
#include <hip/hip_runtime.h>
#include <math.h>

#define FN 128      // F_NODE
#define FE 64       // F_EDGE
#define EPS 1e-5f

typedef __attribute__((ext_vector_type(8))) short bf16x8;
typedef __attribute__((ext_vector_type(4))) float f32x4;

__device__ __forceinline__ float bf2f(unsigned int u_low16) {
    union { unsigned int i; float f; } v; v.i = u_low16 << 16; return v.f;
}
__device__ __forceinline__ float bf2f_hi(unsigned int u) {
    union { unsigned int i; float f; } v; v.i = u & 0xffff0000u; return v.f;
}
__device__ __forceinline__ unsigned short f2bf(float f) {
    union { float f; unsigned int i; } v; v.f = f;
    unsigned int r = v.i + 0x7FFFu + ((v.i >> 16) & 1u);
    return (unsigned short)(r >> 16);
}
__device__ __forceinline__ unsigned int pack2bf(float a, float b) {
    return (unsigned int)f2bf(a) | ((unsigned int)f2bf(b) << 16);
}
// fast sigmoid(f) * softplus(s)
__device__ __forceinline__ float actfn(float f, float s) {
    float sig = __builtin_amdgcn_rcpf(1.0f + __expf(-f));
    float sp = fmaxf(s, 0.0f) + __logf(1.0f + __expf(-fabsf(s)));
    return sig * sp;
}

// ---------------------------------------------------------------------------
// CSR build: histogram -> single-block exclusive scan -> scatter perm
// ---------------------------------------------------------------------------
__global__ void hist_kernel(const int* __restrict__ edst, int* __restrict__ hist, int ne) {
    int e = blockIdx.x * 256 + threadIdx.x;
    if (e < ne) atomicAdd(&hist[edst[e]], 1);
}

__global__ __launch_bounds__(1024) void scan_kernel(
    const int* __restrict__ hist, int* __restrict__ cursor, int nn)
{
    __shared__ int buf[1024];
    int t = threadIdx.x;
    int per = (nn + 1023) >> 10;
    int lo = t * per, hi = min(lo + per, nn);
    int s = 0;
    for (int i = lo; i < hi; i++) s += hist[i];
    buf[t] = s;
    __syncthreads();
    int incl = s;
    for (int off = 1; off < 1024; off <<= 1) {
        int tmp = (t >= off) ? buf[t - off] : 0;
        __syncthreads();
        incl += tmp;
        buf[t] = incl;
        __syncthreads();
    }
    int run = incl - s;   // exclusive base
    for (int i = lo; i < hi; i++) { cursor[i] = run; run += hist[i]; }
}

__global__ void scatter_kernel(const int* __restrict__ edst, int* __restrict__ cursor,
                               int* __restrict__ perm, int ne)
{
    int e = blockIdx.x * 256 + threadIdx.x;
    if (e < ne) {
        int pos = atomicAdd(&cursor[edst[e]], 1);
        perm[pos] = e;
    }
}

// ---------------------------------------------------------------------------
// Node GEMM (MFMA): A[n, 512] = X[n,128] @ [Wf(0:128)|Wf(128:256)|Ws(0:128)|Ws(128:256)]
// Block: 128 M x 64 N, K=128 single pass.  4 waves, each 64M x 32N.
// ---------------------------------------------------------------------------
__global__ __launch_bounds__(256, 4) void node_gemm(
    const float* __restrict__ X, const float* __restrict__ Wf,
    const float* __restrict__ Ws, unsigned short* __restrict__ A, int nnodes)
{
    __shared__ unsigned short Xs[128][128];  // [row][k ^ ((row&7)<<3)] 32 KB
    __shared__ unsigned short Wt[64][128];   // [n][k ^ ((n&7)<<3)]     16 KB
    const int t = threadIdx.x;
    const int m0 = blockIdx.x * 128;
    const int c0 = blockIdx.y * 64;
    const int part = c0 >> 7;
    const float* Bsrc = ((part < 2) ? Wf : Ws) + (part & 1) * 128 * 128 + (c0 & 127);

    // ---- stage X tile (f32 -> bf16, swizzled) ----
    {
        int row = t & 127;
        int kh = t >> 7;                  // 0/1 -> k half
        int m = m0 + row;
        const float* src = X + (size_t)(m < nnodes ? m : 0) * FN + kh * 64;
        int swz = (row & 7) << 3;
#pragma unroll
        for (int q = 0; q < 8; q++) {
            float4 v0 = *(const float4*)(src + q * 8);
            float4 v1 = *(const float4*)(src + q * 8 + 4);
            unsigned int u0 = pack2bf(v0.x, v0.y), u1 = pack2bf(v0.z, v0.w);
            unsigned int u2 = pack2bf(v1.x, v1.y), u3 = pack2bf(v1.z, v1.w);
            int kk = (kh * 64 + q * 8) ^ swz;
            *(uint4*)&Xs[row][kk] = make_uint4(u0, u1, u2, u3);
        }
    }
    // ---- stage W^T tile (swizzled) ----
    {
        int n = t & 63;
        int kq = t >> 6;                  // 0..3
        int swz = (n & 7) << 3;
#pragma unroll
        for (int q = 0; q < 16; q++) {
            int k = kq * 32 + q * 2;
            unsigned int u = pack2bf(Bsrc[(size_t)k * FN + n], Bsrc[(size_t)(k + 1) * FN + n]);
            *(unsigned int*)&Wt[n][k ^ swz] = u;
        }
    }
    __syncthreads();

    const int wv = t >> 6, lane = t & 63;
    const int mw = (wv & 1) * 64;
    const int nw = (wv >> 1) * 32;
    f32x4 acc[4][2];
#pragma unroll
    for (int mt = 0; mt < 4; mt++)
#pragma unroll
        for (int nt = 0; nt < 2; nt++) acc[mt][nt] = (f32x4){0.f, 0.f, 0.f, 0.f};

#pragma unroll
    for (int ks = 0; ks < 4; ks++) {
        int kb = ks * 32 + ((lane >> 4) << 3);
        bf16x8 a[4], b[2];
#pragma unroll
        for (int mt = 0; mt < 4; mt++) {
            int row = mw + mt * 16 + (lane & 15);
            a[mt] = *(const bf16x8*)&Xs[row][kb ^ ((row & 7) << 3)];
        }
#pragma unroll
        for (int nt = 0; nt < 2; nt++) {
            int n = nw + nt * 16 + (lane & 15);
            b[nt] = *(const bf16x8*)&Wt[n][kb ^ ((n & 7) << 3)];
        }
#pragma unroll
        for (int mt = 0; mt < 4; mt++)
#pragma unroll
            for (int nt = 0; nt < 2; nt++)
                acc[mt][nt] = __builtin_amdgcn_mfma_f32_16x16x32_bf16(
                    a[mt], b[nt], acc[mt][nt], 0, 0, 0);
    }

    // ---- C write: n = lane&15, m = (lane>>4)*4 + r ----
#pragma unroll
    for (int mt = 0; mt < 4; mt++) {
        int m = m0 + mw + mt * 16 + ((lane >> 4) << 2);
#pragma unroll
        for (int nt = 0; nt < 2; nt++) {
            int n = c0 + nw + nt * 16 + (lane & 15);
#pragma unroll
            for (int r = 0; r < 4; r++)
                if (m + r < nnodes)
                    A[(size_t)(m + r) * 512 + n] = f2bf(acc[mt][nt][r]);
        }
    }
}

// ---------------------------------------------------------------------------
// Fused edge kernel, v5b: dst-sorted edges; MFMA C-layout; per-nt-group Ebuf;
// ballot-mask run-aggregated scatter.  Compiler memory fences around the
// cross-lane LDS exchange (per-thread alias analysis would otherwise allow
// interleaving next group's ds_write ahead of this group's ds_read).
// ---------------------------------------------------------------------------
__global__ __launch_bounds__(256, 4) void edge_kernel(
    const unsigned short* __restrict__ A, const float* __restrict__ EA,
    const int* __restrict__ esrc, const int* __restrict__ edst,
    const int* __restrict__ perm,
    const float* __restrict__ Wf, const float* __restrict__ Ws,
    const float* __restrict__ bfv, const float* __restrict__ bsv,
    float* __restrict__ summed, int nedges)
{
    __shared__ unsigned short Wlds[2][128][64];  // [mat][outcol][k ^ ((col&7)<<3)] 32 KB
    __shared__ unsigned short Ebuf[4][16][36];   // [wave][edge-in-group][col] 4.6 KB

    const int t = threadIdx.x;
    const int w = t >> 6, lane = t & 63;
    const int ebase = blockIdx.x * 256 + w * 64;

    // ---- stage We^T (rows 256..319), bf16, XOR-swizzled ----
    {
        int col = t & 127;
        int half = t >> 7;
        int swz = (col & 7) << 3;
#pragma unroll 2
        for (int mat = 0; mat < 2; mat++) {
            const float* Wsrc = (mat == 0 ? Wf : Ws) + 256 * FN + col;
#pragma unroll
            for (int q = 0; q < 16; q++) {
                int k = half * 32 + q * 2;
                unsigned int u = pack2bf(Wsrc[(size_t)k * FN], Wsrc[(size_t)(k + 1) * FN]);
                *(unsigned int*)&Wlds[mat][col][k ^ swz] = u;
            }
        }
    }

    int e = ebase + lane;
    bool valid = (e < nedges);
    int eC = valid ? e : (nedges - 1);
    const int pe = perm[eC];
    const int mydst = edst[pe];
    const int mysrc = esrc[pe];

    // run-boundary mask (wave-uniform): bit l set => dst changes after edge l
    unsigned long long flushAfter;
    {
        int prevd = __shfl(mydst, (lane + 63) & 63);
        unsigned long long chg = __ballot(lane > 0 && (mydst != prevd));
        flushAfter = (chg >> 1) | (1ull << 63);
    }

    // per-nt info (edge = nt*16 + (lane&15))
    int vmask[4];
    const unsigned short* dB[4];
    const unsigned short* sB[4];
#pragma unroll
    for (int nt = 0; nt < 4; nt++) {
        int el = nt * 16 + (lane & 15);
        vmask[nt] = (ebase + el < nedges) ? 1 : 0;
        int dn = __shfl(mydst, el);
        int sn = __shfl(mysrc, el);
        dB[nt] = A + (size_t)dn * 512;
        sB[nt] = A + (size_t)sn * 512 + 128;
    }

    // ---- EA fragments (B operand), rows via perm ----
    bf16x8 Eb[4][2];
    {
        const int koff = (lane >> 4) << 3;
#pragma unroll
        for (int nt = 0; nt < 4; nt++) {
            int el = nt * 16 + (lane & 15);
            int pr = __shfl(pe, el);
            const float* p = EA + (size_t)pr * FE + koff;
#pragma unroll
            for (int kk = 0; kk < 2; kk++) {
                float4 v0 = *(const float4*)(p + kk * 32);
                float4 v1 = *(const float4*)(p + kk * 32 + 4);
                bf16x8 b;
                b[0] = (short)f2bf(v0.x); b[1] = (short)f2bf(v0.y);
                b[2] = (short)f2bf(v0.z); b[3] = (short)f2bf(v0.w);
                b[4] = (short)f2bf(v1.x); b[5] = (short)f2bf(v1.y);
                b[6] = (short)f2bf(v1.z); b[7] = (short)f2bf(v1.w);
                Eb[nt][kk] = b;
            }
        }
    }
    __syncthreads();   // Wlds ready — the ONLY block barrier

    const int colo = (lane >> 4) << 2;   // 0,4,8,12
    const int cc = lane & 31;
    const int h = lane >> 5;

#pragma unroll 1
    for (int cb = 0; cb < 4; cb++) {
        const int c0 = cb * 32;

        // ---- issue A-table gathers ----
        uint2 gdf[4][2], gsf[4][2], gds[4][2], gss[4][2];
#pragma unroll
        for (int nt = 0; nt < 4; nt++)
#pragma unroll
            for (int mt = 0; mt < 2; mt++) {
                int off = c0 + mt * 16 + colo;
                gdf[nt][mt] = *(const uint2*)(const void*)(dB[nt] + off);
                gsf[nt][mt] = *(const uint2*)(const void*)(sB[nt] + off);
                gds[nt][mt] = *(const uint2*)(const void*)(dB[nt] + 256 + off);
                gss[nt][mt] = *(const uint2*)(const void*)(sB[nt] + 256 + off);
            }

        // ---- bias ----
        float4 bF[2], bS[2];
#pragma unroll
        for (int mt = 0; mt < 2; mt++) {
            bF[mt] = *(const float4*)(bfv + c0 + mt * 16 + colo);
            bS[mt] = *(const float4*)(bsv + c0 + mt * 16 + colo);
        }

        // ---- MFMA (acc initialized with bias) ----
        f32x4 accF[2][4], accS[2][4];
#pragma unroll
        for (int mt = 0; mt < 2; mt++)
#pragma unroll
            for (int nt = 0; nt < 4; nt++) {
                accF[mt][nt] = (f32x4){bF[mt].x, bF[mt].y, bF[mt].z, bF[mt].w};
                accS[mt][nt] = (f32x4){bS[mt].x, bS[mt].y, bS[mt].z, bS[mt].w};
            }
#pragma unroll
        for (int kk = 0; kk < 2; kk++) {
            bf16x8 aF[2], aS[2];
#pragma unroll
            for (int mt = 0; mt < 2; mt++) {
                int col = c0 + mt * 16 + (lane & 15);
                int kidx = ((kk << 5) + ((lane >> 4) << 3)) ^ ((col & 7) << 3);
                aF[mt] = *(const bf16x8*)&Wlds[0][col][kidx];
                aS[mt] = *(const bf16x8*)&Wlds[1][col][kidx];
            }
#pragma unroll
            for (int mt = 0; mt < 2; mt++)
#pragma unroll
                for (int nt = 0; nt < 4; nt++) {
                    accF[mt][nt] = __builtin_amdgcn_mfma_f32_16x16x32_bf16(
                        aF[mt], Eb[nt][kk], accF[mt][nt], 0, 0, 0);
                    accS[mt][nt] = __builtin_amdgcn_mfma_f32_16x16x32_bf16(
                        aS[mt], Eb[nt][kk], accS[mt][nt], 0, 0, 0);
                }
        }

        // ---- per-nt: gather-add + activation + msg write + scatter ----
#pragma unroll
        for (int nt = 0; nt < 4; nt++) {
            int eg = lane & 15;     // edge-in-group
#pragma unroll
            for (int mt = 0; mt < 2; mt++) {
                f32x4 F = accF[mt][nt], S = accS[mt][nt];
                uint2 a0 = gdf[nt][mt], a1 = gsf[nt][mt];
                uint2 b0 = gds[nt][mt], b1 = gss[nt][mt];
                F[0] += bf2f(a0.x & 0xffffu) + bf2f(a1.x & 0xffffu);
                F[1] += bf2f_hi(a0.x)        + bf2f_hi(a1.x);
                F[2] += bf2f(a0.y & 0xffffu) + bf2f(a1.y & 0xffffu);
                F[3] += bf2f_hi(a0.y)        + bf2f_hi(a1.y);
                S[0] += bf2f(b0.x & 0xffffu) + bf2f(b1.x & 0xffffu);
                S[1] += bf2f_hi(b0.x)        + bf2f_hi(b1.x);
                S[2] += bf2f(b0.y & 0xffffu) + bf2f(b1.y & 0xffffu);
                S[3] += bf2f_hi(b0.y)        + bf2f_hi(b1.y);
                float m0 = actfn(F[0], S[0]);
                float m1 = actfn(F[1], S[1]);
                float m2 = actfn(F[2], S[2]);
                float m3 = actfn(F[3], S[3]);
                if (!vmask[nt]) { m0 = m1 = m2 = m3 = 0.0f; }
                uint2 mw = make_uint2(pack2bf(m0, m1), pack2bf(m2, m3));
                *(uint2*)&Ebuf[w][eg][mt * 16 + colo] = mw;
            }

            // fence: all lanes' msg writes must precede any lane's reads
            asm volatile("" ::: "memory");

            // run-aggregated scatter for this 16-edge group (8 edges per half)
            {
                int ebit0 = nt * 16 + h * 8;
                float run = 0.f;
#pragma unroll
                for (int q = 0; q < 8; q++) {
                    run += bf2f((unsigned int)Ebuf[w][h * 8 + q][cc]);
                    int d = __shfl(mydst, ebit0 + q);
                    bool fl = (q == 7) || ((flushAfter >> (ebit0 + q)) & 1ull);
                    if (fl) {
                        atomicAdd(&summed[(size_t)d * FN + c0 + cc], run);
                        run = 0.f;
                    }
                }
            }

            // fence: reads done before next group's writes may be scheduled
            asm volatile("" ::: "memory");
        }
    }
}

// ---------------------------------------------------------------------------
__global__ __launch_bounds__(256) void finalize_kernel(
    const float* __restrict__ summed, const int* __restrict__ hist,
    const float* xin,
    const float* __restrict__ gamma, const float* __restrict__ beta,
    const float* __restrict__ rmean, const float* __restrict__ rvar,
    float* out, int nnodes)
{
    int idx = blockIdx.x * 256 + threadIdx.x;
    if (idx >= nnodes * FN) return;
    int n = idx >> 7, c = idx & (FN - 1);
    float cnt = (float)hist[n];
    float mean = summed[idx] / fmaxf(cnt, 1.0f);
    float y = (mean - rmean[c]) * rsqrtf(rvar[c] + EPS) * gamma[c] + beta[c] + xin[idx];
    out[idx] = y;
}

// ---------------------------------------------------------------------------
extern "C" void kernel_launch(void* const* d_in, const int* in_sizes, int n_in,
                              void* d_out, int out_size, void* d_ws, size_t ws_size,
                              hipStream_t stream)
{
    const float* x    = (const float*)d_in[0];
    const int*   eidx = (const int*)d_in[1];
    const float* ea   = (const float*)d_in[2];
    const float* Wf1 = (const float*)d_in[3],  * bf1 = (const float*)d_in[4];
    const float* Ws1 = (const float*)d_in[5],  * bs1 = (const float*)d_in[6];
    const float* g1  = (const float*)d_in[7],  * be1 = (const float*)d_in[8];
    const float* rm1 = (const float*)d_in[9],  * rv1 = (const float*)d_in[10];
    const float* Wf2 = (const float*)d_in[11], * bf2 = (const float*)d_in[12];
    const float* Ws2 = (const float*)d_in[13], * bs2 = (const float*)d_in[14];
    const float* g2  = (const float*)d_in[15], * be2 = (const float*)d_in[16];
    const float* rm2 = (const float*)d_in[17], * rv2 = (const float*)d_in[18];
    float* out = (float*)d_out;

    const int NN = in_sizes[0] / FN;
    const int NE = in_sizes[2] / FE;
    const int* esrc = eidx;
    const int* edst = eidx + NE;

    // workspace layout
    char* wsp = (char*)d_ws;
    unsigned short* A = (unsigned short*)wsp;            wsp += (size_t)NN * 512 * 2; // 51.2 MB
    float* summed     = (float*)wsp;                     wsp += (size_t)NN * FN * 4;  // 25.6 MB
    int* hist         = (int*)wsp;                       wsp += (size_t)NN * 4;       // 0.2 MB
    int* perm         = (int*)wsp;                       wsp += (size_t)NE * 4;       // 3.2 MB
    int* cursor       = (int*)summed;  // overlaid: consumed before summed memset

    const int egrid = (NE + 255) / 256;
    const int ngrid = (NN + 127) / 128;
    const int fgrid = (NN * FN + 255) / 256;

    // ---- CSR build (shared by both layers) ----
    (void)hipMemsetAsync(hist, 0, (size_t)NN * 4, stream);
    hist_kernel<<<egrid, 256, 0, stream>>>(edst, hist, NE);
    scan_kernel<<<1, 1024, 0, stream>>>(hist, cursor, NN);
    scatter_kernel<<<egrid, 256, 0, stream>>>(edst, cursor, perm, NE);

    // ---- layer 1 ----
    (void)hipMemsetAsync(summed, 0, (size_t)NN * FN * 4, stream);
    node_gemm<<<dim3(ngrid, 8), 256, 0, stream>>>(x, Wf1, Ws1, A, NN);
    edge_kernel<<<egrid, 256, 0, stream>>>(A, ea, esrc, edst, perm, Wf1, Ws1, bf1, bs1, summed, NE);
    finalize_kernel<<<fgrid, 256, 0, stream>>>(summed, hist, x, g1, be1, rm1, rv1, out, NN);

    // ---- layer 2 ----
    (void)hipMemsetAsync(summed, 0, (size_t)NN * FN * 4, stream);
    node_gemm<<<dim3(ngrid, 8), 256, 0, stream>>>(out, Wf2, Ws2, A, NN);
    edge_kernel<<<egrid, 256, 0, stream>>>(A, ea, esrc, edst, perm, Wf2, Ws2, bf2, bs2, summed, NE);
    finalize_kernel<<<fgrid, 256, 0, stream>>>(summed, hist, out, g2, be2, rm2, rv2, out, NN);
}

// Round 8
// 755.547 us; speedup vs baseline: 1.6309x; 1.6309x over previous
//
#include <hip/hip_runtime.h>
#include <math.h>

#define FN 128      // F_NODE
#define FE 64       // F_EDGE
#define EPS 1e-5f

typedef __attribute__((ext_vector_type(8))) short bf16x8;
typedef __attribute__((ext_vector_type(4))) float f32x4;

__device__ __forceinline__ float bf2f(unsigned int u_low16) {
    union { unsigned int i; float f; } v; v.i = u_low16 << 16; return v.f;
}
__device__ __forceinline__ float bf2f_hi(unsigned int u) {
    union { unsigned int i; float f; } v; v.i = u & 0xffff0000u; return v.f;
}
__device__ __forceinline__ unsigned short f2bf(float f) {
    union { float f; unsigned int i; } v; v.f = f;
    unsigned int r = v.i + 0x7FFFu + ((v.i >> 16) & 1u);
    return (unsigned short)(r >> 16);
}
__device__ __forceinline__ unsigned int pack2bf(float a, float b) {
    return (unsigned int)f2bf(a) | ((unsigned int)f2bf(b) << 16);
}
// fast sigmoid(f) * softplus(s)
__device__ __forceinline__ float actfn(float f, float s) {
    float sig = __builtin_amdgcn_rcpf(1.0f + __expf(-f));
    float sp = fmaxf(s, 0.0f) + __logf(1.0f + __expf(-fabsf(s)));
    return sig * sp;
}

// ---------------------------------------------------------------------------
// CSR build: histogram -> single-block exclusive scan -> scatter perm
// ---------------------------------------------------------------------------
__global__ void hist_kernel(const int* __restrict__ edst, int* __restrict__ hist, int ne) {
    int e = blockIdx.x * 256 + threadIdx.x;
    if (e < ne) atomicAdd(&hist[edst[e]], 1);
}

__global__ __launch_bounds__(1024) void scan_kernel(
    const int* __restrict__ hist, int* __restrict__ cursor, int nn)
{
    __shared__ int buf[1024];
    int t = threadIdx.x;
    int per = (nn + 1023) >> 10;
    int lo = t * per, hi = min(lo + per, nn);
    int s = 0;
    for (int i = lo; i < hi; i++) s += hist[i];
    buf[t] = s;
    __syncthreads();
    int incl = s;
    for (int off = 1; off < 1024; off <<= 1) {
        int tmp = (t >= off) ? buf[t - off] : 0;
        __syncthreads();
        incl += tmp;
        buf[t] = incl;
        __syncthreads();
    }
    int run = incl - s;   // exclusive base
    for (int i = lo; i < hi; i++) { cursor[i] = run; run += hist[i]; }
}

__global__ void scatter_kernel(const int* __restrict__ edst, int* __restrict__ cursor,
                               int* __restrict__ perm, int ne)
{
    int e = blockIdx.x * 256 + threadIdx.x;
    if (e < ne) {
        int pos = atomicAdd(&cursor[edst[e]], 1);
        perm[pos] = e;
    }
}

// ---------------------------------------------------------------------------
// Node GEMM (MFMA): A[n, 512] = X[n,128] @ [Wf(0:128)|Wf(128:256)|Ws(0:128)|Ws(128:256)]
// Block: 128 M x 64 N, K=128 single pass.  4 waves, each 64M x 32N.
// ---------------------------------------------------------------------------
__global__ __launch_bounds__(256, 4) void node_gemm(
    const float* __restrict__ X, const float* __restrict__ Wf,
    const float* __restrict__ Ws, unsigned short* __restrict__ A, int nnodes)
{
    __shared__ unsigned short Xs[128][128];  // [row][k ^ ((row&7)<<3)] 32 KB
    __shared__ unsigned short Wt[64][128];   // [n][k ^ ((n&7)<<3)]     16 KB
    const int t = threadIdx.x;
    const int m0 = blockIdx.x * 128;
    const int c0 = blockIdx.y * 64;
    const int part = c0 >> 7;
    const float* Bsrc = ((part < 2) ? Wf : Ws) + (part & 1) * 128 * 128 + (c0 & 127);

    // ---- stage X tile (f32 -> bf16, swizzled) ----
    {
        int row = t & 127;
        int kh = t >> 7;                  // 0/1 -> k half
        int m = m0 + row;
        const float* src = X + (size_t)(m < nnodes ? m : 0) * FN + kh * 64;
        int swz = (row & 7) << 3;
#pragma unroll
        for (int q = 0; q < 8; q++) {
            float4 v0 = *(const float4*)(src + q * 8);
            float4 v1 = *(const float4*)(src + q * 8 + 4);
            unsigned int u0 = pack2bf(v0.x, v0.y), u1 = pack2bf(v0.z, v0.w);
            unsigned int u2 = pack2bf(v1.x, v1.y), u3 = pack2bf(v1.z, v1.w);
            int kk = (kh * 64 + q * 8) ^ swz;
            *(uint4*)&Xs[row][kk] = make_uint4(u0, u1, u2, u3);
        }
    }
    // ---- stage W^T tile (swizzled) ----
    {
        int n = t & 63;
        int kq = t >> 6;                  // 0..3
        int swz = (n & 7) << 3;
#pragma unroll
        for (int q = 0; q < 16; q++) {
            int k = kq * 32 + q * 2;
            unsigned int u = pack2bf(Bsrc[(size_t)k * FN + n], Bsrc[(size_t)(k + 1) * FN + n]);
            *(unsigned int*)&Wt[n][k ^ swz] = u;
        }
    }
    __syncthreads();

    const int wv = t >> 6, lane = t & 63;
    const int mw = (wv & 1) * 64;
    const int nw = (wv >> 1) * 32;
    f32x4 acc[4][2];
#pragma unroll
    for (int mt = 0; mt < 4; mt++)
#pragma unroll
        for (int nt = 0; nt < 2; nt++) acc[mt][nt] = (f32x4){0.f, 0.f, 0.f, 0.f};

#pragma unroll
    for (int ks = 0; ks < 4; ks++) {
        int kb = ks * 32 + ((lane >> 4) << 3);
        bf16x8 a[4], b[2];
#pragma unroll
        for (int mt = 0; mt < 4; mt++) {
            int row = mw + mt * 16 + (lane & 15);
            a[mt] = *(const bf16x8*)&Xs[row][kb ^ ((row & 7) << 3)];
        }
#pragma unroll
        for (int nt = 0; nt < 2; nt++) {
            int n = nw + nt * 16 + (lane & 15);
            b[nt] = *(const bf16x8*)&Wt[n][kb ^ ((n & 7) << 3)];
        }
#pragma unroll
        for (int mt = 0; mt < 4; mt++)
#pragma unroll
            for (int nt = 0; nt < 2; nt++)
                acc[mt][nt] = __builtin_amdgcn_mfma_f32_16x16x32_bf16(
                    a[mt], b[nt], acc[mt][nt], 0, 0, 0);
    }

    // ---- C write: n = lane&15, m = (lane>>4)*4 + r ----
#pragma unroll
    for (int mt = 0; mt < 4; mt++) {
        int m = m0 + mw + mt * 16 + ((lane >> 4) << 2);
#pragma unroll
        for (int nt = 0; nt < 2; nt++) {
            int n = c0 + nw + nt * 16 + (lane & 15);
#pragma unroll
            for (int r = 0; r < 4; r++)
                if (m + r < nnodes)
                    A[(size_t)(m + r) * 512 + n] = f2bf(acc[mt][nt][r]);
        }
    }
}

// ---------------------------------------------------------------------------
// Fused edge kernel, v6: dst-sorted edges; MFMA C-layout; full-wave Ebuf;
// 32-edge-window run-aggregated scatter (r5 granularity) with ballot mask.
// ---------------------------------------------------------------------------
__global__ __launch_bounds__(256, 3) void edge_kernel(
    const unsigned short* __restrict__ A, const float* __restrict__ EA,
    const int* __restrict__ esrc, const int* __restrict__ edst,
    const int* __restrict__ perm,
    const float* __restrict__ Wf, const float* __restrict__ Ws,
    const float* __restrict__ bfv, const float* __restrict__ bsv,
    float* __restrict__ summed, int nedges)
{
    __shared__ unsigned short Wlds[2][128][64];  // [mat][outcol][k ^ ((col&7)<<3)] 32 KB
    __shared__ unsigned short Ebuf[4][64][36];   // [wave][edge][col] bf16 msg, 18.4 KB

    const int t = threadIdx.x;
    const int w = t >> 6, lane = t & 63;
    const int ebase = blockIdx.x * 256 + w * 64;

    // ---- stage We^T (rows 256..319), bf16, XOR-swizzled ----
    {
        int col = t & 127;
        int half = t >> 7;
        int swz = (col & 7) << 3;
#pragma unroll 2
        for (int mat = 0; mat < 2; mat++) {
            const float* Wsrc = (mat == 0 ? Wf : Ws) + 256 * FN + col;
#pragma unroll
            for (int q = 0; q < 16; q++) {
                int k = half * 32 + q * 2;
                unsigned int u = pack2bf(Wsrc[(size_t)k * FN], Wsrc[(size_t)(k + 1) * FN]);
                *(unsigned int*)&Wlds[mat][col][k ^ swz] = u;
            }
        }
    }

    int e = ebase + lane;
    bool valid = (e < nedges);
    int eC = valid ? e : (nedges - 1);
    const int pe = perm[eC];
    const int mydst = edst[pe];
    const int mysrc = esrc[pe];

    // run-boundary mask (wave-uniform): bit l set => dst changes after edge l
    unsigned long long flushAfter;
    {
        int prevd = __shfl(mydst, (lane + 63) & 63);
        unsigned long long chg = __ballot(lane > 0 && (mydst != prevd));
        flushAfter = (chg >> 1) | (1ull << 63) | (1ull << 31);
    }

    // per-nt info (edge = nt*16 + (lane&15))
    int vmask[4];
    const unsigned short* dB[4];
    const unsigned short* sB[4];
#pragma unroll
    for (int nt = 0; nt < 4; nt++) {
        int el = nt * 16 + (lane & 15);
        vmask[nt] = (ebase + el < nedges) ? 1 : 0;
        int dn = __shfl(mydst, el);
        int sn = __shfl(mysrc, el);
        dB[nt] = A + (size_t)dn * 512;
        sB[nt] = A + (size_t)sn * 512 + 128;
    }

    // ---- EA fragments (B operand), rows via perm ----
    bf16x8 Eb[4][2];
    {
        const int koff = (lane >> 4) << 3;
#pragma unroll
        for (int nt = 0; nt < 4; nt++) {
            int el = nt * 16 + (lane & 15);
            int pr = __shfl(pe, el);
            const float* p = EA + (size_t)pr * FE + koff;
#pragma unroll
            for (int kk = 0; kk < 2; kk++) {
                float4 v0 = *(const float4*)(p + kk * 32);
                float4 v1 = *(const float4*)(p + kk * 32 + 4);
                bf16x8 b;
                b[0] = (short)f2bf(v0.x); b[1] = (short)f2bf(v0.y);
                b[2] = (short)f2bf(v0.z); b[3] = (short)f2bf(v0.w);
                b[4] = (short)f2bf(v1.x); b[5] = (short)f2bf(v1.y);
                b[6] = (short)f2bf(v1.z); b[7] = (short)f2bf(v1.w);
                Eb[nt][kk] = b;
            }
        }
    }
    __syncthreads();   // Wlds ready — the ONLY block barrier

    const int colo = (lane >> 4) << 2;   // 0,4,8,12
    const int cc = lane & 31;
    const int h = lane >> 5;

#pragma unroll 1
    for (int cb = 0; cb < 4; cb++) {
        const int c0 = cb * 32;

        // ---- issue A-table gathers ----
        uint2 gdf[4][2], gsf[4][2], gds[4][2], gss[4][2];
#pragma unroll
        for (int nt = 0; nt < 4; nt++)
#pragma unroll
            for (int mt = 0; mt < 2; mt++) {
                int off = c0 + mt * 16 + colo;
                gdf[nt][mt] = *(const uint2*)(const void*)(dB[nt] + off);
                gsf[nt][mt] = *(const uint2*)(const void*)(sB[nt] + off);
                gds[nt][mt] = *(const uint2*)(const void*)(dB[nt] + 256 + off);
                gss[nt][mt] = *(const uint2*)(const void*)(sB[nt] + 256 + off);
            }

        // ---- bias ----
        float4 bF[2], bS[2];
#pragma unroll
        for (int mt = 0; mt < 2; mt++) {
            bF[mt] = *(const float4*)(bfv + c0 + mt * 16 + colo);
            bS[mt] = *(const float4*)(bsv + c0 + mt * 16 + colo);
        }

        // ---- MFMA (acc initialized with bias) ----
        f32x4 accF[2][4], accS[2][4];
#pragma unroll
        for (int mt = 0; mt < 2; mt++)
#pragma unroll
            for (int nt = 0; nt < 4; nt++) {
                accF[mt][nt] = (f32x4){bF[mt].x, bF[mt].y, bF[mt].z, bF[mt].w};
                accS[mt][nt] = (f32x4){bS[mt].x, bS[mt].y, bS[mt].z, bS[mt].w};
            }
#pragma unroll
        for (int kk = 0; kk < 2; kk++) {
            bf16x8 aF[2], aS[2];
#pragma unroll
            for (int mt = 0; mt < 2; mt++) {
                int col = c0 + mt * 16 + (lane & 15);
                int kidx = ((kk << 5) + ((lane >> 4) << 3)) ^ ((col & 7) << 3);
                aF[mt] = *(const bf16x8*)&Wlds[0][col][kidx];
                aS[mt] = *(const bf16x8*)&Wlds[1][col][kidx];
            }
#pragma unroll
            for (int mt = 0; mt < 2; mt++)
#pragma unroll
                for (int nt = 0; nt < 4; nt++) {
                    accF[mt][nt] = __builtin_amdgcn_mfma_f32_16x16x32_bf16(
                        aF[mt], Eb[nt][kk], accF[mt][nt], 0, 0, 0);
                    accS[mt][nt] = __builtin_amdgcn_mfma_f32_16x16x32_bf16(
                        aS[mt], Eb[nt][kk], accS[mt][nt], 0, 0, 0);
                }
        }

        // ---- gather-add + activation + msg write (all groups, C-layout) ----
#pragma unroll
        for (int nt = 0; nt < 4; nt++) {
            int edge = nt * 16 + (lane & 15);
#pragma unroll
            for (int mt = 0; mt < 2; mt++) {
                f32x4 F = accF[mt][nt], S = accS[mt][nt];
                uint2 a0 = gdf[nt][mt], a1 = gsf[nt][mt];
                uint2 b0 = gds[nt][mt], b1 = gss[nt][mt];
                F[0] += bf2f(a0.x & 0xffffu) + bf2f(a1.x & 0xffffu);
                F[1] += bf2f_hi(a0.x)        + bf2f_hi(a1.x);
                F[2] += bf2f(a0.y & 0xffffu) + bf2f(a1.y & 0xffffu);
                F[3] += bf2f_hi(a0.y)        + bf2f_hi(a1.y);
                S[0] += bf2f(b0.x & 0xffffu) + bf2f(b1.x & 0xffffu);
                S[1] += bf2f_hi(b0.x)        + bf2f_hi(b1.x);
                S[2] += bf2f(b0.y & 0xffffu) + bf2f(b1.y & 0xffffu);
                S[3] += bf2f_hi(b0.y)        + bf2f_hi(b1.y);
                float m0 = actfn(F[0], S[0]);
                float m1 = actfn(F[1], S[1]);
                float m2 = actfn(F[2], S[2]);
                float m3 = actfn(F[3], S[3]);
                if (!vmask[nt]) { m0 = m1 = m2 = m3 = 0.0f; }
                uint2 mw = make_uint2(pack2bf(m0, m1), pack2bf(m2, m3));
                *(uint2*)&Ebuf[w][edge][mt * 16 + colo] = mw;
            }
        }

        // fence: all lanes' msg writes precede any lane's scatter reads
        asm volatile("" ::: "memory");

        // ---- run-aggregated scatter: each half-wave scans its 32 edges,
        //      one contiguous 32-dword atomic per dst-run ----
        {
            int ebit0 = h << 5;
            float run = 0.f;
#pragma unroll 1
            for (int q = 0; q < 32; q++) {
                int e2 = ebit0 + q;
                run += bf2f((unsigned int)Ebuf[w][e2][cc]);
                int d = __shfl(mydst, e2);
                if ((flushAfter >> e2) & 1ull) {
                    atomicAdd(&summed[(size_t)d * FN + c0 + cc], run);
                    run = 0.f;
                }
            }
        }

        // fence: scatter reads done before next chunk's writes are scheduled
        asm volatile("" ::: "memory");
    }
}

// ---------------------------------------------------------------------------
__global__ __launch_bounds__(256) void finalize_kernel(
    const float* __restrict__ summed, const int* __restrict__ hist,
    const float* xin,
    const float* __restrict__ gamma, const float* __restrict__ beta,
    const float* __restrict__ rmean, const float* __restrict__ rvar,
    float* out, int nnodes)
{
    int idx = blockIdx.x * 256 + threadIdx.x;
    if (idx >= nnodes * FN) return;
    int n = idx >> 7, c = idx & (FN - 1);
    float cnt = (float)hist[n];
    float mean = summed[idx] / fmaxf(cnt, 1.0f);
    float y = (mean - rmean[c]) * rsqrtf(rvar[c] + EPS) * gamma[c] + beta[c] + xin[idx];
    out[idx] = y;
}

// ---------------------------------------------------------------------------
extern "C" void kernel_launch(void* const* d_in, const int* in_sizes, int n_in,
                              void* d_out, int out_size, void* d_ws, size_t ws_size,
                              hipStream_t stream)
{
    const float* x    = (const float*)d_in[0];
    const int*   eidx = (const int*)d_in[1];
    const float* ea   = (const float*)d_in[2];
    const float* Wf1 = (const float*)d_in[3],  * bf1 = (const float*)d_in[4];
    const float* Ws1 = (const float*)d_in[5],  * bs1 = (const float*)d_in[6];
    const float* g1  = (const float*)d_in[7],  * be1 = (const float*)d_in[8];
    const float* rm1 = (const float*)d_in[9],  * rv1 = (const float*)d_in[10];
    const float* Wf2 = (const float*)d_in[11], * bf2 = (const float*)d_in[12];
    const float* Ws2 = (const float*)d_in[13], * bs2 = (const float*)d_in[14];
    const float* g2  = (const float*)d_in[15], * be2 = (const float*)d_in[16];
    const float* rm2 = (const float*)d_in[17], * rv2 = (const float*)d_in[18];
    float* out = (float*)d_out;

    const int NN = in_sizes[0] / FN;
    const int NE = in_sizes[2] / FE;
    const int* esrc = eidx;
    const int* edst = eidx + NE;

    // workspace layout
    char* wsp = (char*)d_ws;
    unsigned short* A = (unsigned short*)wsp;            wsp += (size_t)NN * 512 * 2; // 51.2 MB
    float* summed     = (float*)wsp;                     wsp += (size_t)NN * FN * 4;  // 25.6 MB
    int* hist         = (int*)wsp;                       wsp += (size_t)NN * 4;       // 0.2 MB
    int* perm         = (int*)wsp;                       wsp += (size_t)NE * 4;       // 3.2 MB
    int* cursor       = (int*)summed;  // overlaid: consumed before summed memset

    const int egrid = (NE + 255) / 256;
    const int ngrid = (NN + 127) / 128;
    const int fgrid = (NN * FN + 255) / 256;

    // ---- CSR build (shared by both layers) ----
    (void)hipMemsetAsync(hist, 0, (size_t)NN * 4, stream);
    hist_kernel<<<egrid, 256, 0, stream>>>(edst, hist, NE);
    scan_kernel<<<1, 1024, 0, stream>>>(hist, cursor, NN);
    scatter_kernel<<<egrid, 256, 0, stream>>>(edst, cursor, perm, NE);

    // ---- layer 1 ----
    (void)hipMemsetAsync(summed, 0, (size_t)NN * FN * 4, stream);
    node_gemm<<<dim3(ngrid, 8), 256, 0, stream>>>(x, Wf1, Ws1, A, NN);
    edge_kernel<<<egrid, 256, 0, stream>>>(A, ea, esrc, edst, perm, Wf1, Ws1, bf1, bs1, summed, NE);
    finalize_kernel<<<fgrid, 256, 0, stream>>>(summed, hist, x, g1, be1, rm1, rv1, out, NN);

    // ---- layer 2 ----
    (void)hipMemsetAsync(summed, 0, (size_t)NN * FN * 4, stream);
    node_gemm<<<dim3(ngrid, 8), 256, 0, stream>>>(out, Wf2, Ws2, A, NN);
    edge_kernel<<<egrid, 256, 0, stream>>>(A, ea, esrc, edst, perm, Wf2, Ws2, bf2, bs2, summed, NE);
    finalize_kernel<<<fgrid, 256, 0, stream>>>(summed, hist, out, g2, be2, rm2, rv2, out, NN);
}